// Round 1
// baseline (4091.265 us; speedup 1.0000x reference)
//
#include <hip/hip_runtime.h>
#include <math.h>

// Problem constants (fixed by setup_inputs)
#define BQ 2048
#define DD 1024
#define CC 65536
#define KSEL 8
#define NSTRIPE 32
#define SC (CC / NSTRIPE)   // 2048 cols per stripe
#define TM 128
#define TN 128
#define TKC 16
#define NTILES (SC / TN)    // 16
#define LCAND 8             // per-stripe top-L (exact union property needs 8)
#define TRES 16             // candidates rescored in fp64 per row

// ---------------- workspace layout (bytes) ----------------
// 0        : double qinv[BQ]              (16384)
// 16384    : double kinv[CC]              (524288)
// 540672   : float  counts[CC]            (262144)
// 802816   : float  cand_val[BQ*32*8]     (2097152)
// 2899968  : int    cand_idx[BQ*32*8]     (2097152)
// 4997120  : int    sel_idx[BQ*16]        (131072)
// 5128192  : double sel_val[BQ*16]        (262144)
// 5390336  : int    topk_idx[BQ*8]        (65536)   -> total 5455872 B

__global__ __launch_bounds__(256) void norms_zero_kernel(
    const float* __restrict__ q, const float* __restrict__ keys,
    double* __restrict__ qinv, double* __restrict__ kinv,
    float* __restrict__ counts)
{
    const int gtid = blockIdx.x * 256 + threadIdx.x;
    if (gtid < CC) counts[gtid] = 0.0f;
    const int wave = gtid >> 6;
    const int lane = threadIdx.x & 63;
    const float4* src;
    double* dst;
    if (wave < CC) {
        src = (const float4*)(keys + (size_t)wave * DD);
        dst = kinv + wave;
    } else {
        const int r = wave - CC;
        if (r >= BQ) return;               // wave-uniform guard
        src = (const float4*)(q + (size_t)r * DD);
        dst = qinv + r;
    }
    double s = 0.0;
#pragma unroll
    for (int u = 0; u < 4; ++u) {
        float4 v = src[lane + 64 * u];
        s += (double)v.x * v.x + (double)v.y * v.y +
             (double)v.z * v.z + (double)v.w * v.w;
    }
    for (int off = 32; off > 0; off >>= 1) s += __shfl_down(s, off);
    if (lane == 0) {
        double n = sqrt(s);
        *dst = 1.0 / fmax(n, 1e-12);       // matches F.normalize eps semantics
    }
}

// First pass: fp32 tiled sims + fused exact per-stripe top-8 per row.
// grid = (BQ/TM, NSTRIPE), block = 256.
__global__ __launch_bounds__(256) void sims_topk_kernel(
    const float* __restrict__ q, const float* __restrict__ keys,
    const double* __restrict__ qinv, const double* __restrict__ kinv,
    float* __restrict__ cand_val, int* __restrict__ cand_idx)
{
    __shared__ float Qs[TKC][TM];      // transposed: [kk][row]  8 KB
    __shared__ float Ks[TKC][TN];      // transposed: [kk][col]  8 KB
    __shared__ float tilebuf[TM][65];  // 64-col chunk, +1 pad   33.3 KB
    __shared__ float qsc[TM];
    __shared__ float ksc[TN];

    const int tid = threadIdx.x;
    const int m0 = blockIdx.x * TM;
    const int sbase = blockIdx.y * SC;
    const int ty = tid >> 4;           // 0..15
    const int tx = tid & 15;           // 0..15
    const int r0 = ty * 8;
    const int c0l = tx * 8;
    const int sr = tid >> 1;           // staging row 0..127
    const int skb = (tid & 1) * 8;     // staging k-base {0,8}

    float tv[LCAND];
    int ti[LCAND];
#pragma unroll
    for (int l = 0; l < LCAND; ++l) { tv[l] = -3.0e38f; ti[l] = 0; }
    float minv = -3.0e38f;
    int minpos = 0;

    if (tid < TM) qsc[tid] = (float)qinv[m0 + tid];

    const float* qrow = q + (size_t)(m0 + sr) * DD + skb;

    for (int nt = 0; nt < NTILES; ++nt) {
        const int cb = sbase + nt * TN;
        __syncthreads();                       // protect ksc/tilebuf readers
        if (tid < TN) ksc[tid] = (float)kinv[cb + tid];

        float acc[8][8];
#pragma unroll
        for (int i = 0; i < 8; ++i)
#pragma unroll
            for (int j = 0; j < 8; ++j) acc[i][j] = 0.0f;

        const float* krow = keys + (size_t)(cb + sr) * DD + skb;

        for (int kc = 0; kc < DD / TKC; ++kc) {
            const int k0 = kc * TKC;
            float4 qa0 = *(const float4*)(qrow + k0);
            float4 qa1 = *(const float4*)(qrow + k0 + 4);
            float4 ka0 = *(const float4*)(krow + k0);
            float4 ka1 = *(const float4*)(krow + k0 + 4);
            __syncthreads();                   // prev tile reads done
            Qs[skb + 0][sr] = qa0.x; Qs[skb + 1][sr] = qa0.y;
            Qs[skb + 2][sr] = qa0.z; Qs[skb + 3][sr] = qa0.w;
            Qs[skb + 4][sr] = qa1.x; Qs[skb + 5][sr] = qa1.y;
            Qs[skb + 6][sr] = qa1.z; Qs[skb + 7][sr] = qa1.w;
            Ks[skb + 0][sr] = ka0.x; Ks[skb + 1][sr] = ka0.y;
            Ks[skb + 2][sr] = ka0.z; Ks[skb + 3][sr] = ka0.w;
            Ks[skb + 4][sr] = ka1.x; Ks[skb + 5][sr] = ka1.y;
            Ks[skb + 6][sr] = ka1.z; Ks[skb + 7][sr] = ka1.w;
            __syncthreads();
#pragma unroll
            for (int kk = 0; kk < TKC; ++kk) {
                float4 a0 = *(const float4*)&Qs[kk][r0];
                float4 a1 = *(const float4*)&Qs[kk][r0 + 4];
                float4 b0 = *(const float4*)&Ks[kk][c0l];
                float4 b1 = *(const float4*)&Ks[kk][c0l + 4];
                float a[8] = {a0.x, a0.y, a0.z, a0.w, a1.x, a1.y, a1.z, a1.w};
                float b[8] = {b0.x, b0.y, b0.z, b0.w, b1.x, b1.y, b1.z, b1.w};
#pragma unroll
                for (int i = 0; i < 8; ++i)
#pragma unroll
                    for (int j = 0; j < 8; ++j)
                        acc[i][j] = fmaf(a[i], b[j], acc[i][j]);
            }
        }

        // epilogue: scale by inv-norms, run per-row top-8 over two 64-col chunks
        for (int cc2 = 0; cc2 < 2; ++cc2) {
            __syncthreads();
            if ((tx >> 3) == cc2) {
                const int cl = (tx & 7) * 8;
#pragma unroll
                for (int i = 0; i < 8; ++i) {
                    const float qs_ = qsc[r0 + i];
#pragma unroll
                    for (int j = 0; j < 8; ++j)
                        tilebuf[r0 + i][cl + j] = acc[i][j] * qs_ * ksc[c0l + j];
                }
            }
            __syncthreads();
            if (tid < TM) {
                const int gc0 = cb + cc2 * 64;
                for (int j = 0; j < 64; ++j) {
                    float v = tilebuf[tid][j];
                    if (v > minv) {
                        tv[minpos] = v; ti[minpos] = gc0 + j;
                        minv = tv[0]; minpos = 0;
#pragma unroll
                        for (int l = 1; l < LCAND; ++l)
                            if (tv[l] < minv) { minv = tv[l]; minpos = l; }
                    }
                }
            }
        }
    }

    if (tid < TM) {
        size_t base = ((size_t)(m0 + tid) * NSTRIPE + blockIdx.y) * LCAND;
#pragma unroll
        for (int l = 0; l < LCAND; ++l) {
            cand_val[base + l] = tv[l];
            cand_idx[base + l] = ti[l];
        }
    }
}

__device__ __forceinline__ bool better_f(float a, int ai, float b, int bi) {
    return (a > b) || (a == b && ai < bi);
}

// One wave per row: top-16 of 256 candidates by first-pass value.
__global__ __launch_bounds__(256) void merge_kernel(
    const float* __restrict__ cand_val, const int* __restrict__ cand_idx,
    int* __restrict__ sel_idx)
{
    const int row = (blockIdx.x * 256 + threadIdx.x) >> 6;
    const int lane = threadIdx.x & 63;
    const float* cv = cand_val + (size_t)row * (NSTRIPE * LCAND);
    const int* ci = cand_idx + (size_t)row * (NSTRIPE * LCAND);
    float v[4]; int id[4];
#pragma unroll
    for (int u = 0; u < 4; ++u) {
        v[u] = cv[lane + 64 * u];
        id[u] = ci[lane + 64 * u];
    }
    for (int r = 0; r < TRES; ++r) {
        float bv = -3.4e38f; int bid = 0x7fffffff;
#pragma unroll
        for (int u = 0; u < 4; ++u)
            if (better_f(v[u], id[u], bv, bid)) { bv = v[u]; bid = id[u]; }
        for (int off = 32; off > 0; off >>= 1) {
            float ov = __shfl_down(bv, off);
            int oid = __shfl_down(bid, off);
            if (better_f(ov, oid, bv, bid)) { bv = ov; bid = oid; }
        }
        bid = __shfl(bid, 0);
#pragma unroll
        for (int u = 0; u < 4; ++u)
            if (id[u] == bid) {                 // ids are unique per row
                v[u] = -3.4e38f;
                sel_idx[row * TRES + r] = bid;
            }
    }
}

// One wave per (row, candidate): exact fp64 cosine sim.
__global__ __launch_bounds__(256) void rescore_kernel(
    const float* __restrict__ q, const float* __restrict__ keys,
    const double* __restrict__ qinv, const double* __restrict__ kinv,
    const int* __restrict__ sel_idx, double* __restrict__ sel_val)
{
    const int pair = (blockIdx.x * 256 + threadIdx.x) >> 6;
    const int lane = threadIdx.x & 63;
    const int b = pair >> 4;
    const int c = sel_idx[pair];
    const float4* qr = (const float4*)(q + (size_t)b * DD);
    const float4* kr = (const float4*)(keys + (size_t)c * DD);
    double s = 0.0;
#pragma unroll
    for (int u = 0; u < 4; ++u) {
        float4 a = qr[lane + 64 * u];
        float4 k4 = kr[lane + 64 * u];
        s += (double)a.x * k4.x + (double)a.y * k4.y +
             (double)a.z * k4.z + (double)a.w * k4.w;
    }
    for (int off = 32; off > 0; off >>= 1) s += __shfl_down(s, off);
    if (lane == 0) sel_val[pair] = s * qinv[b] * kinv[c];
}

// One thread per row: sort 16 fp64 candidates desc (tie -> lower idx), emit top-8.
__global__ __launch_bounds__(256) void finalize_kernel(
    const double* __restrict__ sel_val, const int* __restrict__ sel_idx,
    int* __restrict__ topk_idx, float* __restrict__ counts)
{
    const int b = blockIdx.x * 256 + threadIdx.x;
    if (b >= BQ) return;
    double bv[KSEL]; int bi[KSEL];
#pragma unroll
    for (int j = 0; j < KSEL; ++j) { bv[j] = -1.0e300; bi[j] = 0x7fffffff; }
    for (int t = 0; t < TRES; ++t) {
        double v = sel_val[b * TRES + t];
        int idx = sel_idx[b * TRES + t];
        int p = KSEL;
        while (p > 0 && (v > bv[p - 1] || (v == bv[p - 1] && idx < bi[p - 1]))) --p;
        if (p < KSEL) {
            for (int s = KSEL - 1; s > p; --s) { bv[s] = bv[s - 1]; bi[s] = bi[s - 1]; }
            bv[p] = v; bi[p] = idx;
        }
    }
    for (int j = 0; j < KSEL; ++j) {
        topk_idx[b * KSEL + j] = bi[j];
        atomicAdd(&counts[bi[j]], 1.0f);
    }
}

// One block per (b, j): copy key row and value row (bit-exact gather).
__global__ __launch_bounds__(256) void gather_kernel(
    const float* __restrict__ keys, const float* __restrict__ values,
    const int* __restrict__ topk_idx, float* __restrict__ out_k,
    float* __restrict__ out_v)
{
    const int pair = blockIdx.x;               // b*8 + j
    const int c = topk_idx[pair];
    const int t = threadIdx.x;
    const float4* ks = (const float4*)(keys + (size_t)c * DD);
    const float4* vs = (const float4*)(values + (size_t)c * DD);
    float4* ok = (float4*)out_k + (size_t)pair * (DD / 4);
    float4* ov = (float4*)out_v + (size_t)pair * (DD / 4);
    ok[t] = ks[t];
    ov[t] = vs[t];
}

__global__ __launch_bounds__(256) void usage_kernel(
    const float* __restrict__ usage_in, const float* __restrict__ counts,
    float* __restrict__ out_u)
{
    const int c = blockIdx.x * 256 + threadIdx.x;
    out_u[c] = usage_in[c] + counts[c];
}

extern "C" void kernel_launch(void* const* d_in, const int* in_sizes, int n_in,
                              void* d_out, int out_size, void* d_ws, size_t ws_size,
                              hipStream_t stream)
{
    const float* q      = (const float*)d_in[0];
    const float* keys   = (const float*)d_in[1];
    const float* values = (const float*)d_in[2];
    const float* usage  = (const float*)d_in[3];
    // d_in[4] is k == 8, hardcoded.

    char* ws = (char*)d_ws;
    double* qinv    = (double*)(ws + 0);
    double* kinv    = (double*)(ws + 16384);
    float* counts   = (float*)(ws + 540672);
    float* cand_val = (float*)(ws + 802816);
    int* cand_idx   = (int*)(ws + 2899968);
    int* sel_idx    = (int*)(ws + 4997120);
    double* sel_val = (double*)(ws + 5128192);
    int* topk       = (int*)(ws + 5390336);

    float* out_k = (float*)d_out;
    float* out_v = out_k + (size_t)BQ * KSEL * DD;
    float* out_u = out_v + (size_t)BQ * KSEL * DD;

    norms_zero_kernel<<<(CC + BQ) / 4, 256, 0, stream>>>(q, keys, qinv, kinv, counts);

    dim3 g2(BQ / TM, NSTRIPE);
    sims_topk_kernel<<<g2, 256, 0, stream>>>(q, keys, qinv, kinv, cand_val, cand_idx);

    merge_kernel<<<BQ / 4, 256, 0, stream>>>(cand_val, cand_idx, sel_idx);

    rescore_kernel<<<(BQ * TRES) / 4, 256, 0, stream>>>(q, keys, qinv, kinv,
                                                        sel_idx, sel_val);

    finalize_kernel<<<BQ / 256, 256, 0, stream>>>(sel_val, sel_idx, topk, counts);

    gather_kernel<<<BQ * KSEL, 256, 0, stream>>>(keys, values, topk, out_k, out_v);

    usage_kernel<<<CC / 256, 256, 0, stream>>>(usage, counts, out_u);
}

// Round 2
// 1267.788 us; speedup vs baseline: 3.2271x; 3.2271x over previous
//
#include <hip/hip_runtime.h>
#include <math.h>

// Problem constants (fixed by setup_inputs)
#define BQ 2048
#define DD 1024
#define CC 65536
#define KSEL 8
#define NSTRIPE 32
#define SC (CC / NSTRIPE)   // 2048 cols per stripe
#define GTM 128
#define GTN 128
#define GBK 32
#define NTILES (SC / GTN)   // 16 col-tiles per stripe
#define LCAND 8             // per-stripe top-L (union property needs 8)
#define TRES 32             // candidates rescored in fp64 per row

typedef unsigned int u32;
typedef unsigned short ushort_t;
typedef __attribute__((ext_vector_type(8))) short bf16x8;
typedef __attribute__((ext_vector_type(4))) float f32x4;

// ---------------- workspace layout (bytes), total 6,832,128 ----------------
// 0        : double qinv[BQ]                (16384)
// 16384    : double kinv[CC]                (524288)
// 540672   : ushort qn[BQ*DD]               (4194304)   dead after gemm; aliased:
//   540672 :   float counts[CC]             (262144)
//   802816 :   int   sel_idx[BQ*32]         (262144)
//   1064960:   double sel_val[BQ*32]        (524288)
//   1589248:   int   topk[BQ*8]             (65536)
// 4734976  : uint  cand[BQ*NSTRIPE*LCAND]   (2097152)
// kn (bf16, 128 MB) lives in d_out[0 .. 134217728) — overwritten by gather at end.

__device__ __forceinline__ ushort_t f2bf(float f) {
    u32 u = __builtin_bit_cast(u32, f);
    return (ushort_t)((u + 0x7FFFu + ((u >> 16) & 1u)) >> 16);
}

__device__ __forceinline__ void gl_lds16(const ushort_t* g, ushort_t* l) {
    __builtin_amdgcn_global_load_lds(
        (const __attribute__((address_space(1))) u32*)g,
        (__attribute__((address_space(3))) u32*)l, 16, 0, 0);
}

// fp64 inverse L2 norms for q (2048 rows) and keys (65536 rows). One wave/row.
__global__ __launch_bounds__(256) void norms_kernel(
    const float* __restrict__ q, const float* __restrict__ keys,
    double* __restrict__ qinv, double* __restrict__ kinv)
{
    const int gtid = blockIdx.x * 256 + threadIdx.x;
    const int wave = gtid >> 6;
    const int lane = threadIdx.x & 63;
    const float4* src;
    double* dst;
    if (wave < CC) {
        src = (const float4*)(keys + (size_t)wave * DD);
        dst = kinv + wave;
    } else {
        const int r = wave - CC;
        if (r >= BQ) return;               // wave-uniform guard
        src = (const float4*)(q + (size_t)r * DD);
        dst = qinv + r;
    }
    double s = 0.0;
#pragma unroll
    for (int u = 0; u < 4; ++u) {
        float4 v = src[lane + 64 * u];
        s += (double)v.x * v.x + (double)v.y * v.y +
             (double)v.z * v.z + (double)v.w * v.w;
    }
    for (int off = 32; off > 0; off >>= 1) s += __shfl_down(s, off);
    if (lane == 0) {
        double n = sqrt(s);
        *dst = 1.0 / fmax(n, 1e-12);
    }
}

// Fold normalization and convert to bf16: one block per row (keys rows then q rows).
__global__ __launch_bounds__(256) void convert_kernel(
    const float* __restrict__ q, const float* __restrict__ keys,
    const double* __restrict__ qinv, const double* __restrict__ kinv,
    ushort_t* __restrict__ qn, ushort_t* __restrict__ kn)
{
    const int row = blockIdx.x;
    const int t = threadIdx.x;
    const float4* src;
    ushort_t* dst;
    float inv;
    if (row < CC) {
        src = (const float4*)(keys + (size_t)row * DD);
        dst = kn + (size_t)row * DD;
        inv = (float)kinv[row];
    } else {
        const int r = row - CC;
        src = (const float4*)(q + (size_t)r * DD);
        dst = qn + (size_t)r * DD;
        inv = (float)qinv[r];
    }
    float4 v = src[t];
    ushort4 o;
    o.x = f2bf(v.x * inv); o.y = f2bf(v.y * inv);
    o.z = f2bf(v.z * inv); o.w = f2bf(v.w * inv);
    ((ushort4*)dst)[t] = o;
}

// MFMA bf16 GEMM (m97 structure) fused with exact per-stripe top-8 per row.
// grid = (BQ/128, NSTRIPE), block = 256 (4 waves, 2x2 wave grid).
__global__ __launch_bounds__(256, 2) void gemm_topk_kernel(
    const ushort_t* __restrict__ qn, const ushort_t* __restrict__ kn,
    unsigned* __restrict__ cand)
{
    __shared__ ushort_t As[GTM * GBK];     // row-major [m][k]  8 KB
    __shared__ ushort_t Bs[GTN * GBK];     // row-major [n][k]  8 KB
    __shared__ float tilebuf[GTM][65];     // 64-col chunk, +1 pad  33.3 KB

    const int tid = threadIdx.x;
    const int wid = tid >> 6;
    const int lane = tid & 63;
    const int wy = wid >> 1, wx = wid & 1;
    const int l15 = lane & 15, quad = lane >> 4;
    const int m0 = blockIdx.x * GTM;
    const int sbase = blockIdx.y * SC;

    // staging: 512 16B segments per tile; thread handles e and e+256.
    const int e0 = tid, e1 = tid + 256;
    const ushort_t* gA0 = qn + (size_t)(m0 + (e0 >> 2)) * DD + (e0 & 3) * 8;
    const ushort_t* gA1 = qn + (size_t)(m0 + (e1 >> 2)) * DD + (e1 & 3) * 8;
    ushort_t* lA0 = As + e0 * 8;
    ushort_t* lA1 = As + e1 * 8;
    ushort_t* lB0 = Bs + e0 * 8;
    ushort_t* lB1 = Bs + e1 * 8;

    float tv[LCAND];
    int ti[LCAND];
#pragma unroll
    for (int l = 0; l < LCAND; ++l) { tv[l] = -3.0e38f; ti[l] = 0; }
    float minv = -3.0e38f;
    int minpos = 0;

    for (int nt = 0; nt < NTILES; ++nt) {
        const int cbase = sbase + nt * GTN;
        const ushort_t* gB0 = kn + (size_t)(cbase + (e0 >> 2)) * DD + (e0 & 3) * 8;
        const ushort_t* gB1 = kn + (size_t)(cbase + (e1 >> 2)) * DD + (e1 & 3) * 8;

        f32x4 acc[4][4];
#pragma unroll
        for (int i = 0; i < 4; ++i)
#pragma unroll
            for (int j = 0; j < 4; ++j) acc[i][j] = (f32x4)0.0f;

        for (int kt = 0; kt < DD / GBK; ++kt) {
            const int k0 = kt * GBK;
            __syncthreads();                 // As/Bs readers of prev step done
            gl_lds16(gA0 + k0, lA0);
            gl_lds16(gA1 + k0, lA1);
            gl_lds16(gB0 + k0, lB0);
            gl_lds16(gB1 + k0, lB1);
            __syncthreads();                 // compiler drains vmcnt before barrier

            bf16x8 af[4], bfr[4];
#pragma unroll
            for (int ri = 0; ri < 4; ++ri)
                af[ri] = *(const bf16x8*)(As + (wy * 64 + ri * 16 + l15) * GBK + quad * 8);
#pragma unroll
            for (int ci = 0; ci < 4; ++ci)
                bfr[ci] = *(const bf16x8*)(Bs + (wx * 64 + ci * 16 + l15) * GBK + quad * 8);
#pragma unroll
            for (int ri = 0; ri < 4; ++ri)
#pragma unroll
                for (int ci = 0; ci < 4; ++ci)
                    acc[ri][ci] = __builtin_amdgcn_mfma_f32_16x16x32_bf16(
                        af[ri], bfr[ci], acc[ri][ci], 0, 0, 0);
        }

        // epilogue: dump 64-col chunks to LDS, scan exact running top-8 per row
        for (int cc2 = 0; cc2 < 2; ++cc2) {
            __syncthreads();                 // prior scan readers done
            if (wx == cc2) {
#pragma unroll
                for (int ri = 0; ri < 4; ++ri)
#pragma unroll
                    for (int ci = 0; ci < 4; ++ci)
#pragma unroll
                        for (int r = 0; r < 4; ++r)
                            tilebuf[wy * 64 + ri * 16 + quad * 4 + r][ci * 16 + l15] =
                                acc[ri][ci][r];
            }
            __syncthreads();
            if (tid < GTM) {
                const int gc0 = cbase + cc2 * 64;
                for (int j = 0; j < 64; ++j) {
                    float v = tilebuf[tid][j];
                    if (v > minv) {
                        tv[minpos] = v; ti[minpos] = gc0 + j;
                        minv = tv[0]; minpos = 0;
#pragma unroll
                        for (int l = 1; l < LCAND; ++l)
                            if (tv[l] < minv) { minv = tv[l]; minpos = l; }
                    }
                }
            }
        }
    }

    if (tid < GTM) {
        unsigned* dst = cand + (size_t)(m0 + tid) * (NSTRIPE * LCAND) + blockIdx.y * LCAND;
#pragma unroll
        for (int l = 0; l < LCAND; ++l)
            dst[l] = ((unsigned)f2bf(tv[l]) << 16) | (unsigned)(ti[l] & 0xFFFF);
    }
}

// One wave per row: top-32 of 256 packed candidates (signed-int compare works:
// all real candidate sims > 0 -> packed positive; padding is negative).
// Also zeroes counts[] (runs after gemm, counts aliases dead qn space).
__global__ __launch_bounds__(256) void merge_kernel(
    const int* __restrict__ cand, int* __restrict__ sel_idx,
    float* __restrict__ counts)
{
    const int gid = blockIdx.x * 256 + threadIdx.x;
    if (gid < CC) counts[gid] = 0.0f;
    const int row = gid >> 6;
    const int lane = threadIdx.x & 63;
    const int* cv = cand + (size_t)row * (NSTRIPE * LCAND);
    int v[4];
#pragma unroll
    for (int u = 0; u < 4; ++u) v[u] = cv[lane + 64 * u];
    for (int r = 0; r < TRES; ++r) {
        int bv = v[0];
#pragma unroll
        for (int u = 1; u < 4; ++u) bv = max(bv, v[u]);
#pragma unroll
        for (int off = 1; off < 64; off <<= 1) bv = max(bv, __shfl_xor(bv, off));
#pragma unroll
        for (int u = 0; u < 4; ++u)
            if (v[u] == bv) v[u] = (int)0x80000000;   // packed values unique per row
        if (lane == 0) sel_idx[row * TRES + r] = bv & 0xFFFF;
    }
}

// One wave per (row, candidate): exact fp64 cosine sim on ORIGINAL fp32 data.
__global__ __launch_bounds__(256) void rescore_kernel(
    const float* __restrict__ q, const float* __restrict__ keys,
    const double* __restrict__ qinv, const double* __restrict__ kinv,
    const int* __restrict__ sel_idx, double* __restrict__ sel_val)
{
    const int pair = (blockIdx.x * 256 + threadIdx.x) >> 6;
    const int lane = threadIdx.x & 63;
    const int b = pair >> 5;                           // TRES = 32
    const int c = sel_idx[pair];
    const float4* qr = (const float4*)(q + (size_t)b * DD);
    const float4* kr = (const float4*)(keys + (size_t)c * DD);
    double s = 0.0;
#pragma unroll
    for (int u = 0; u < 4; ++u) {
        float4 a = qr[lane + 64 * u];
        float4 k4 = kr[lane + 64 * u];
        s += (double)a.x * k4.x + (double)a.y * k4.y +
             (double)a.z * k4.z + (double)a.w * k4.w;
    }
    for (int off = 32; off > 0; off >>= 1) s += __shfl_down(s, off);
    if (lane == 0) sel_val[pair] = s * qinv[b] * kinv[c];
}

// One thread per row: insertion-sort 32 fp64 candidates desc (tie -> lower idx).
__global__ __launch_bounds__(256) void finalize_kernel(
    const double* __restrict__ sel_val, const int* __restrict__ sel_idx,
    int* __restrict__ topk_idx, float* __restrict__ counts)
{
    const int b = blockIdx.x * 256 + threadIdx.x;
    if (b >= BQ) return;
    double bv[KSEL]; int bi[KSEL];
#pragma unroll
    for (int j = 0; j < KSEL; ++j) { bv[j] = -1.0e300; bi[j] = 0x7fffffff; }
    for (int t = 0; t < TRES; ++t) {
        double v = sel_val[b * TRES + t];
        int idx = sel_idx[b * TRES + t];
        int p = KSEL;
        while (p > 0 && (v > bv[p - 1] || (v == bv[p - 1] && idx < bi[p - 1]))) --p;
        if (p < KSEL) {
            for (int s = KSEL - 1; s > p; --s) { bv[s] = bv[s - 1]; bi[s] = bi[s - 1]; }
            bv[p] = v; bi[p] = idx;
        }
    }
    for (int j = 0; j < KSEL; ++j) {
        topk_idx[b * KSEL + j] = bi[j];
        atomicAdd(&counts[bi[j]], 1.0f);
    }
}

// One block per (b, j): bit-exact row copies from ORIGINAL keys/values.
// Overwrites the kn scratch living in d_out — must run after gemm (it does).
__global__ __launch_bounds__(256) void gather_kernel(
    const float* __restrict__ keys, const float* __restrict__ values,
    const int* __restrict__ topk_idx, float* __restrict__ out_k,
    float* __restrict__ out_v)
{
    const int pair = blockIdx.x;               // b*8 + j
    const int c = topk_idx[pair];
    const int t = threadIdx.x;
    const float4* ks = (const float4*)(keys + (size_t)c * DD);
    const float4* vs = (const float4*)(values + (size_t)c * DD);
    float4* ok = (float4*)out_k + (size_t)pair * (DD / 4);
    float4* ov = (float4*)out_v + (size_t)pair * (DD / 4);
    ok[t] = ks[t];
    ov[t] = vs[t];
}

__global__ __launch_bounds__(256) void usage_kernel(
    const float* __restrict__ usage_in, const float* __restrict__ counts,
    float* __restrict__ out_u)
{
    const int c = blockIdx.x * 256 + threadIdx.x;
    out_u[c] = usage_in[c] + counts[c];
}

extern "C" void kernel_launch(void* const* d_in, const int* in_sizes, int n_in,
                              void* d_out, int out_size, void* d_ws, size_t ws_size,
                              hipStream_t stream)
{
    const float* q      = (const float*)d_in[0];
    const float* keys   = (const float*)d_in[1];
    const float* values = (const float*)d_in[2];
    const float* usage  = (const float*)d_in[3];
    // d_in[4] is k == 8, hardcoded.

    char* ws = (char*)d_ws;
    double* qinv     = (double*)(ws + 0);
    double* kinv     = (double*)(ws + 16384);
    ushort_t* qn     = (ushort_t*)(ws + 540672);
    // aliases into dead-after-gemm qn space:
    float* counts    = (float*)(ws + 540672);
    int* sel_idx     = (int*)(ws + 802816);
    double* sel_val  = (double*)(ws + 1064960);
    int* topk        = (int*)(ws + 1589248);
    unsigned* cand   = (unsigned*)(ws + 4734976);

    float* out_k = (float*)d_out;
    float* out_v = out_k + (size_t)BQ * KSEL * DD;
    float* out_u = out_v + (size_t)BQ * KSEL * DD;
    ushort_t* kn = (ushort_t*)d_out;   // 128 MB scratch, dies before gather

    norms_kernel<<<(CC + BQ) / 4, 256, 0, stream>>>(q, keys, qinv, kinv);

    convert_kernel<<<CC + BQ, 256, 0, stream>>>(q, keys, qinv, kinv, qn, kn);

    dim3 g2(BQ / GTM, NSTRIPE);
    gemm_topk_kernel<<<g2, 256, 0, stream>>>(qn, kn, cand);

    merge_kernel<<<BQ / 4, 256, 0, stream>>>((const int*)cand, sel_idx, counts);

    rescore_kernel<<<(BQ * TRES) / 4, 256, 0, stream>>>(q, keys, qinv, kinv,
                                                        sel_idx, sel_val);

    finalize_kernel<<<BQ / 256, 256, 0, stream>>>(sel_val, sel_idx, topk, counts);

    gather_kernel<<<BQ * KSEL, 256, 0, stream>>>(keys, values, topk, out_k, out_v);

    usage_kernel<<<CC / 256, 256, 0, stream>>>(usage, counts, out_u);
}